// Round 4
// baseline (113.305 us; speedup 1.0000x reference)
//
#include <hip/hip_runtime.h>

#define BLOCK 8
#define NGRID 512

// ---------------------------------------------------------------------------
// Compile-time replication of
//   np.random.RandomState(0).choice(np.array([1.0,3.0],f32), size=(512,8))
// (MT19937 legacy scalar seeding, one 32-bit draw per value, value = draw&1).
// Bit i of pattern byte = element i: g[i] = bit ? 3.0f : 1.0f.
// Dedup (first occurrence) is argmax-neutral. kenc = 255 - dedup_index, so
// "ties -> max kenc" == numpy first-max.
// ---------------------------------------------------------------------------
struct Base {
  bool exists[256];
  unsigned char kenc[256];
  unsigned char kpat[256];  // kenc -> pattern byte
  int nd;
};

constexpr int popcount8c(int v) {
  int p = 0;
  for (int i = 0; i < 8; ++i) p += (v >> i) & 1;
  return p;
}

constexpr Base make_base() {
  Base t{};
  // --- MT19937, numpy legacy scalar seed 0 ---
  unsigned mt[624] = {};
  {
    unsigned s = 0u;
    for (int i = 0; i < 624; ++i) {
      mt[i] = s;
      s = 1812433253u * (s ^ (s >> 30)) + (unsigned)(i + 1);
    }
  }
  int pos = 624;
  int nd = 0;
  for (int j = 0; j < NGRID; ++j) {
    unsigned char b = 0;
    for (int i = 0; i < BLOCK; ++i) {
      if (pos == 624) {
        for (int k = 0; k < 624; ++k) {
          int k1 = (k + 1 < 624) ? k + 1 : 0;
          int k397 = (k + 397 < 624) ? k + 397 : k + 397 - 624;
          unsigned y = (mt[k] & 0x80000000u) | (mt[k1] & 0x7fffffffu);
          unsigned v = mt[k397] ^ (y >> 1);
          if (y & 1u) v ^= 0x9908b0dfu;
          mt[k] = v;
        }
        pos = 0;
      }
      unsigned y = mt[pos++];
      y ^= y >> 11;
      y ^= (y << 7) & 0x9d2c5680u;
      y ^= (y << 15) & 0xefc60000u;
      y ^= y >> 18;
      if (y & 1u) b |= (unsigned char)(1u << i);
    }
    if (!t.exists[b]) {
      t.exists[b] = true;
      t.kenc[b] = (unsigned char)(255 - nd);
      t.kpat[255 - nd] = b;
      ++nd;
    }
  }
  t.nd = nd;
  return t;
}

constexpr Base BS = make_base();

// epilogue gather table: kenc -> pattern byte (struct-init of __constant__)
struct Pat { unsigned char p[256]; };
constexpr Pat make_pat() {
  Pat t{};
  for (int i = 0; i < 256; ++i) t.p[i] = BS.kpat[i];
  return t;
}
__device__ __constant__ Pat GP = make_pat();

// ---------------------------------------------------------------------------
// Loop-form schedule (identical to the R3 table, proven absmax 0.0078125):
// 32 chunks = the 32 low-5-bit prefix families (each <= 8 members).
// Per chunk (48 dwords):
//   [0..4]   prefix coefs c_l (levels 0..4), f32 bits, c in {1.0, 3.0}
//   [5..28]  member coefs: m=0..7, levels 5..7 -> v[5 + 3m + (l-5)]
//   [29..44] member score consts: {negnf, rcf} per member (pads: {0, -1})
//   [45,46]  klut lo/hi: kenc byte per member slot
//   [47]     pad
// Members sorted by kenc ASCENDING (pads kenc=0 first) so the fixed-order
// eq-scan "last equal wins" == max kenc == numpy min-k tie-break.
// Bit-exactness argument unchanged from R3 (fma(a,1.0,s)==fl(a+s); uniform
// Markstein == 1-op path for pow2 norms; pads score -2*dd <= -0.0 never win).
// ---------------------------------------------------------------------------
struct CTab { unsigned v[32 * 48]; };

constexpr unsigned fb(float f) { return __builtin_bit_cast(unsigned, f); }

constexpr CTab make_ctab() {
  CTab t{};
  for (int P = 0; P < 32; ++P) {
    const int base = P * 48;
    for (int l = 0; l < 5; ++l)
      t.v[base + l] = fb(((P >> l) & 1) ? 3.0f : 1.0f);
    // gather family members (high 3 bits free)
    unsigned char mp[8] = {};
    int mk[8] = {};
    bool pf[8] = {};
    int n = 0;
    for (int hi = 0; hi < 8; ++hi) {
      int pat = P | (hi << 5);
      if (BS.exists[pat]) { mp[n] = (unsigned char)pat; mk[n] = BS.kenc[pat]; pf[n] = false; ++n; }
    }
    for (int i = n; i < 8; ++i) { mp[i] = (unsigned char)P; mk[i] = 0; pf[i] = true; }
    // insertion sort by kenc ascending (parallel arrays)
    for (int i = 1; i < 8; ++i) {
      int ki = mk[i]; unsigned char pi = mp[i]; bool fi = pf[i];
      int p = i - 1;
      while (p >= 0 && mk[p] > ki) {
        mk[p + 1] = mk[p]; mp[p + 1] = mp[p]; pf[p + 1] = pf[p]; --p;
      }
      mk[p + 1] = ki; mp[p + 1] = pi; pf[p + 1] = fi;
    }
    for (int m = 0; m < 8; ++m) {
      for (int dl = 0; dl < 3; ++dl)
        t.v[base + 5 + 3 * m + dl] = fb(((mp[m] >> (5 + dl)) & 1) ? 3.0f : 1.0f);
      float negnf = 0.0f, rcf = -1.0f;
      if (!pf[m]) {
        const int pc = popcount8c(mp[m]);
        const float nf = (float)(8 * (1 + pc));
        negnf = -nf;
        rcf = 1.0f / nf;  // RN reciprocal at compile time (same as before)
      }
      t.v[base + 29 + 2 * m] = fb(negnf);
      t.v[base + 30 + 2 * m] = fb(rcf);
    }
    unsigned lo = 0, hi2 = 0;
    for (int m = 0; m < 4; ++m) lo |= (unsigned)mk[m] << (8 * m);
    for (int m = 4; m < 8; ++m) hi2 |= (unsigned)mk[m] << (8 * (m - 4));
    t.v[base + 45] = lo;
    t.v[base + 46] = hi2;
    t.v[base + 47] = 0u;
  }
  return t;
}

__device__ __constant__ CTab CT = make_ctab();

__device__ __forceinline__ float uf(unsigned u) { return __uint_as_float(u); }

// One block's chunk step: identical op sequence to R3 (bit-exact proven).
// Table values arrive via wave-uniform s_loads (SGPR operands).
__device__ __forceinline__ void chunk_step(const unsigned* __restrict__ tb,
                                           const float (&a)[BLOCK],
                                           float& gb, int& gk) {
  // shared low-5-bit prefix chain (levels 0..4)
  float pre = 0.0f;
#pragma unroll
  for (int l = 0; l < 5; ++l)
    pre = __builtin_fmaf(a[l], uf(tb[l]), pre);

  // 8 members: 3-fma suffix chain + dd + uniform Markstein score
  float sc[8];
#pragma unroll
  for (int m = 0; m < 8; ++m) {
    float d = pre;
    d = __builtin_fmaf(a[5], uf(tb[5 + 3 * m + 0]), d);
    d = __builtin_fmaf(a[6], uf(tb[5 + 3 * m + 1]), d);
    d = __builtin_fmaf(a[7], uf(tb[5 + 3 * m + 2]), d);
    float dd = d * d;
    float rcf = uf(tb[30 + 2 * m]);
    float q0 = dd * rcf;
    float r = __builtin_fmaf(uf(tb[29 + 2 * m]), q0, dd);
    sc[m] = __builtin_fmaf(r, rcf, q0);
  }

  float cm = __builtin_fmaxf(
      __builtin_fmaxf(__builtin_fmaxf(sc[0], sc[1]), __builtin_fmaxf(sc[2], sc[3])),
      __builtin_fmaxf(__builtin_fmaxf(sc[4], sc[5]), __builtin_fmaxf(sc[6], sc[7])));

  int ck = 0;
#pragma unroll
  for (int m = 0; m < 8; ++m)  // kenc ascending: last equal = max kenc = min k
    ck = (sc[m] == cm) ? m : ck;

  unsigned ksel = (ck & 4) ? tb[46] : tb[45];
  int kenc = (int)((ksel >> ((ck & 3) << 3)) & 0xFFu);

  bool r2 = (cm > gb) || ((cm == gb) && (kenc > gk));
  gb = r2 ? cm : gb;
  gk = r2 ? kenc : gk;
}

// Epilogue for one block: identical op sequence to R0..R3 (bit-exact proven).
__device__ __forceinline__ void epilogue(const float (&a)[BLOCK], unsigned sbits,
                                         int gk, float4& o0, float4& o1) {
  unsigned int bits = (unsigned int)GP.p[gk];  // divergent 1-byte gather, L1

  float q[BLOCK];
#pragma unroll
  for (int i = 0; i < BLOCK; ++i) q[i] = ((bits >> i) & 1u) ? 3.0f : 1.0f;

  float p[BLOCK];
#pragma unroll
  for (int i = 0; i < BLOCK; ++i) p[i] = a[i] * q[i];
  float num = ((p[0] + p[1]) + (p[2] + p[3])) + ((p[4] + p[5]) + (p[6] + p[7]));

  int popc = __popc(bits);
  float normf = (float)(8 + (popc << 3));
  float scale = num / normf;  // IEEE CR f32 divide (once)

  float o[BLOCK];
#pragma unroll
  for (int i = 0; i < BLOCK; ++i) {
    float wvi = __uint_as_float(__float_as_uint(a[i]) | (((sbits >> i) & 1u) << 31));
    float sg = (wvi > 0.0f) ? 1.0f : ((wvi < 0.0f) ? -1.0f : 0.0f);
    float deq = (scale * q[i]) * sg;
    o[i] = wvi + (deq - wvi);  // w + stop_gradient(deq - w)
  }
  o0 = float4{o[0], o[1], o[2], o[3]};
  o1 = float4{o[4], o[5], o[6], o[7]};
}

// 2 blocks/thread (two independent scalar dependency chains per wave -> fills
// the latency bubbles that left R3 at 50% VALUBusy), shared per-chunk table
// s_loads, #pragma unroll 2 on the chunk loop so next-chunk s_loads schedule
// under current-chunk math. Body ~5 KB: I$-resident. Grid: 1024 WGs = 4
// WG/CU = 4 waves/SIMD x 2 chains = 8 chains/SIMD.
__global__ __launch_bounds__(256, 4) void _IQ2XSQuantWeight_12945031430379_kernel(
    const float* __restrict__ w, float* __restrict__ out, int nt) {
  int t = blockIdx.x * blockDim.x + threadIdx.x;
  if (t >= nt) return;

  // two adjacent 8-elem blocks per thread: 64 contiguous bytes per lane
  const float4* wp = reinterpret_cast<const float4*>(w) + (size_t)4 * t;
  float4 A0 = wp[0];
  float4 A1 = wp[1];
  float4 B0 = wp[2];
  float4 B1 = wp[3];
  float wvA[BLOCK] = {A0.x, A0.y, A0.z, A0.w, A1.x, A1.y, A1.z, A1.w};
  float wvB[BLOCK] = {B0.x, B0.y, B0.z, B0.w, B1.x, B1.y, B1.z, B1.w};

  float aA[BLOCK], aB[BLOCK];
  unsigned sbA = 0u, sbB = 0u;
#pragma unroll
  for (int i = 0; i < BLOCK; ++i) {
    unsigned ua = __float_as_uint(wvA[i]);
    unsigned ub = __float_as_uint(wvB[i]);
    sbA |= (ua >> 31) << i;
    sbB |= (ub >> 31) << i;
    aA[i] = __uint_as_float(ua & 0x7fffffffu);  // == fabsf
    aB[i] = __uint_as_float(ub & 0x7fffffffu);
  }

  float gbA = -1.0f, gbB = -1.0f;
  int gkA = 0, gkB = 0;

#pragma unroll 2
  for (int c = 0; c < 32; ++c) {
    const unsigned* tb = CT.v + c * 48;
    chunk_step(tb, aA, gbA, gkA);
    chunk_step(tb, aB, gbB, gkB);
  }

  float4 oA0, oA1, oB0, oB1;
  epilogue(aA, sbA, gkA, oA0, oA1);
  epilogue(aB, sbB, gkB, oB0, oB1);

  float4* op = reinterpret_cast<float4*>(out) + (size_t)4 * t;
  op[0] = oA0;
  op[1] = oA1;
  op[2] = oB0;
  op[3] = oB1;
}

extern "C" void kernel_launch(void* const* d_in, const int* in_sizes, int n_in,
                              void* d_out, int out_size, void* d_ws, size_t ws_size,
                              hipStream_t stream) {
  (void)n_in; (void)d_ws; (void)ws_size; (void)out_size;
  const float* w = (const float*)d_in[0];
  float* out = (float*)d_out;
  int n = in_sizes[0];
  int nb = n / BLOCK;      // 8-elem quant blocks (524288: even)
  int nt = nb / 2;         // 2 blocks per thread
  int threads = 256;
  int blocks = (nt + threads - 1) / threads;
  _IQ2XSQuantWeight_12945031430379_kernel<<<blocks, threads, 0, stream>>>(w, out, nt);
}

// Round 5
// 104.831 us; speedup vs baseline: 1.0808x; 1.0808x over previous
//
#include <hip/hip_runtime.h>

#define BLOCK 8
#define NGRID 512

// ---------------------------------------------------------------------------
// Compile-time replication of
//   np.random.RandomState(0).choice(np.array([1.0,3.0],f32), size=(512,8))
// (MT19937 legacy scalar seeding, one 32-bit draw per value, value = draw&1).
// Bit i of pattern byte = element i: g[i] = bit ? 3.0f : 1.0f.
// Dedup (first occurrence) is argmax-neutral. kenc = 255 - dedup_index, so
// "ties -> max kenc" == numpy first-max.
// ---------------------------------------------------------------------------
struct Base {
  bool exists[256];
  unsigned char kenc[256];
  unsigned char kpat[256];  // kenc -> pattern byte
  int nd;
};

constexpr int popcount8c(int v) {
  int p = 0;
  for (int i = 0; i < 8; ++i) p += (v >> i) & 1;
  return p;
}

constexpr Base make_base() {
  Base t{};
  // --- MT19937, numpy legacy scalar seed 0 ---
  unsigned mt[624] = {};
  {
    unsigned s = 0u;
    for (int i = 0; i < 624; ++i) {
      mt[i] = s;
      s = 1812433253u * (s ^ (s >> 30)) + (unsigned)(i + 1);
    }
  }
  int pos = 624;
  int nd = 0;
  for (int j = 0; j < NGRID; ++j) {
    unsigned char b = 0;
    for (int i = 0; i < BLOCK; ++i) {
      if (pos == 624) {
        for (int k = 0; k < 624; ++k) {
          int k1 = (k + 1 < 624) ? k + 1 : 0;
          int k397 = (k + 397 < 624) ? k + 397 : k + 397 - 624;
          unsigned y = (mt[k] & 0x80000000u) | (mt[k1] & 0x7fffffffu);
          unsigned v = mt[k397] ^ (y >> 1);
          if (y & 1u) v ^= 0x9908b0dfu;
          mt[k] = v;
        }
        pos = 0;
      }
      unsigned y = mt[pos++];
      y ^= y >> 11;
      y ^= (y << 7) & 0x9d2c5680u;
      y ^= (y << 15) & 0xefc60000u;
      y ^= y >> 18;
      if (y & 1u) b |= (unsigned char)(1u << i);
    }
    if (!t.exists[b]) {
      t.exists[b] = true;
      t.kenc[b] = (unsigned char)(255 - nd);
      t.kpat[255 - nd] = b;
      ++nd;
    }
  }
  t.nd = nd;
  return t;
}

constexpr Base BS = make_base();

// epilogue gather table: kenc -> pattern byte
struct Pat { unsigned char p[256]; };
constexpr Pat make_pat() {
  Pat t{};
  for (int i = 0; i < 256; ++i) t.p[i] = BS.kpat[i];
  return t;
}
__device__ __constant__ Pat GP = make_pat();

// ---------------------------------------------------------------------------
// Chunk table (identical values to the proven R3/R4 table, absmax 0.0078125):
// 32 chunks = the 32 low-5-bit prefix families (each <= 8 members).
// Per chunk (48 dwords):
//   [0..4]   prefix coefs c_l (levels 0..4), f32 bits, c in {1.0, 3.0}
//   [5..28]  member coefs: m=0..7, levels 5..7 -> v[5 + 3m + (l-5)]
//   [29..44] member score consts: {negnf, rcf} per member (pads: {0, -1})
//   [45,46]  klut lo/hi: kenc byte per member slot
//   [47]     pad
// Members sorted by kenc ASCENDING (pads kenc=0 first) so the fixed-order
// eq-scan "last equal wins" == max kenc == numpy min-k tie-break.
// Bit-exactness argument unchanged from R3 (fma(a,1.0,s)==fl(a+s); uniform
// Markstein == 1-op path for pow2 norms; pads score -2*dd <= -0.0 never win).
// ---------------------------------------------------------------------------
struct CTab { unsigned v[32 * 48]; };

constexpr unsigned fb(float f) { return __builtin_bit_cast(unsigned, f); }

constexpr CTab make_ctab() {
  CTab t{};
  for (int P = 0; P < 32; ++P) {
    const int base = P * 48;
    for (int l = 0; l < 5; ++l)
      t.v[base + l] = fb(((P >> l) & 1) ? 3.0f : 1.0f);
    // gather family members (high 3 bits free)
    unsigned char mp[8] = {};
    int mk[8] = {};
    bool pf[8] = {};
    int n = 0;
    for (int hi = 0; hi < 8; ++hi) {
      int pat = P | (hi << 5);
      if (BS.exists[pat]) { mp[n] = (unsigned char)pat; mk[n] = BS.kenc[pat]; pf[n] = false; ++n; }
    }
    for (int i = n; i < 8; ++i) { mp[i] = (unsigned char)P; mk[i] = 0; pf[i] = true; }
    // insertion sort by kenc ascending (parallel arrays)
    for (int i = 1; i < 8; ++i) {
      int ki = mk[i]; unsigned char pi = mp[i]; bool fi = pf[i];
      int p = i - 1;
      while (p >= 0 && mk[p] > ki) {
        mk[p + 1] = mk[p]; mp[p + 1] = mp[p]; pf[p + 1] = pf[p]; --p;
      }
      mk[p + 1] = ki; mp[p + 1] = pi; pf[p + 1] = fi;
    }
    for (int m = 0; m < 8; ++m) {
      for (int dl = 0; dl < 3; ++dl)
        t.v[base + 5 + 3 * m + dl] = fb(((mp[m] >> (5 + dl)) & 1) ? 3.0f : 1.0f);
      float negnf = 0.0f, rcf = -1.0f;
      if (!pf[m]) {
        const int pc = popcount8c(mp[m]);
        const float nf = (float)(8 * (1 + pc));
        negnf = -nf;
        rcf = 1.0f / nf;  // RN reciprocal at compile time (same as before)
      }
      t.v[base + 29 + 2 * m] = fb(negnf);
      t.v[base + 30 + 2 * m] = fb(rcf);
    }
    unsigned lo = 0, hi2 = 0;
    for (int m = 0; m < 4; ++m) lo |= (unsigned)mk[m] << (8 * m);
    for (int m = 4; m < 8; ++m) hi2 |= (unsigned)mk[m] << (8 * (m - 4));
    t.v[base + 45] = lo;
    t.v[base + 46] = hi2;
    t.v[base + 47] = 0u;
  }
  return t;
}

__device__ __constant__ CTab CT = make_ctab();

// One block's chunk step from a VGPR-resident table copy tb[48] (values
// bit-identical to R3/R4's SGPR path; transport does not affect rounding).
__device__ __forceinline__ void chunk_step(const float (&tb)[48],
                                           const float (&a)[BLOCK],
                                           float& gb, int& gk) {
  // shared low-5-bit prefix chain (levels 0..4)
  float pre = 0.0f;
#pragma unroll
  for (int l = 0; l < 5; ++l)
    pre = __builtin_fmaf(a[l], tb[l], pre);

  // 8 members: 3-fma suffix chain + dd + uniform Markstein score
  float sc[8];
#pragma unroll
  for (int m = 0; m < 8; ++m) {
    float d = pre;
    d = __builtin_fmaf(a[5], tb[5 + 3 * m + 0], d);
    d = __builtin_fmaf(a[6], tb[5 + 3 * m + 1], d);
    d = __builtin_fmaf(a[7], tb[5 + 3 * m + 2], d);
    float dd = d * d;
    float rcf = tb[30 + 2 * m];
    float q0 = dd * rcf;
    float r = __builtin_fmaf(tb[29 + 2 * m], q0, dd);
    sc[m] = __builtin_fmaf(r, rcf, q0);
  }

  // max over 8 (associativity-free: fmax over non-NaN values; +-0 ties
  // resolve identically through == and > below). max3-friendly shape.
  float cm = __builtin_fmaxf(
      __builtin_fmaxf(__builtin_fmaxf(sc[0], sc[1]), __builtin_fmaxf(sc[2], sc[3])),
      __builtin_fmaxf(__builtin_fmaxf(sc[4], sc[5]), __builtin_fmaxf(sc[6], sc[7])));

  int ck = 0;
#pragma unroll
  for (int m = 0; m < 8; ++m)  // kenc ascending: last equal = max kenc = min k
    ck = (sc[m] == cm) ? m : ck;

  unsigned ksel = (ck & 4) ? __float_as_uint(tb[46]) : __float_as_uint(tb[45]);
  int kenc = (int)((ksel >> ((ck & 3) << 3)) & 0xFFu);

  bool r2 = (cm > gb) || ((cm == gb) && (kenc > gk));
  gb = r2 ? cm : gb;
  gk = r2 ? kenc : gk;
}

// Epilogue for one block: identical op sequence to R0..R4 (bit-exact proven).
__device__ __forceinline__ void epilogue(const float (&a)[BLOCK], unsigned sbits,
                                         int gk, float4& o0, float4& o1) {
  unsigned int bits = (unsigned int)GP.p[gk];  // divergent 1-byte gather, L1

  float q[BLOCK];
#pragma unroll
  for (int i = 0; i < BLOCK; ++i) q[i] = ((bits >> i) & 1u) ? 3.0f : 1.0f;

  float p[BLOCK];
#pragma unroll
  for (int i = 0; i < BLOCK; ++i) p[i] = a[i] * q[i];
  float num = ((p[0] + p[1]) + (p[2] + p[3])) + ((p[4] + p[5]) + (p[6] + p[7]));

  int popc = __popc(bits);
  float normf = (float)(8 + (popc << 3));
  float scale = num / normf;  // IEEE CR f32 divide (once)

  float o[BLOCK];
#pragma unroll
  for (int i = 0; i < BLOCK; ++i) {
    float wvi = __uint_as_float(__float_as_uint(a[i]) | (((sbits >> i) & 1u) << 31));
    float sg = (wvi > 0.0f) ? 1.0f : ((wvi < 0.0f) ? -1.0f : 0.0f);
    float deq = (scale * q[i]) * sg;
    o[i] = wvi + (deq - wvi);  // w + stop_gradient(deq - w)
  }
  o0 = float4{o[0], o[1], o[2], o[3]};
  o1 = float4{o[4], o[5], o[6], o[7]};
}

// R5: table transport SGPR/K$ -> LDS. R3/R4 stalled at ~50% VALUBusy
// independent of occupancy (8 vs 3 waves/SIMD) => shared-resource stall on
// the per-CU scalar fetch path. LDS broadcast reads (ds_read_b128, wave-
// uniform address) are per-wave and deeply queueable; 4 resident waves/SIMD
// hide the ~120cyc latency under ~360cyc of chunk math. 2 blocks/thread
// amortizes the LDS traffic (R4 already showed 2-block+s_load == R3, so any
// gain here attributes to the transport change).
__global__ __launch_bounds__(256, 4) void _IQ2XSQuantWeight_12945031430379_kernel(
    const float* __restrict__ w, float* __restrict__ out, int nt) {
  __shared__ __align__(16) float lds_f[32 * 48];

  int tid = threadIdx.x;
  // one-time table stage: 1536 dwords / 256 threads = 6 each
#pragma unroll
  for (int j = 0; j < 6; ++j)
    lds_f[tid + 256 * j] = __uint_as_float(CT.v[tid + 256 * j]);
  __syncthreads();

  int t = blockIdx.x * blockDim.x + tid;
  if (t >= nt) return;

  // two adjacent 8-elem blocks per thread: 64 contiguous bytes per lane
  const float4* wp = reinterpret_cast<const float4*>(w) + (size_t)4 * t;
  float4 A0 = wp[0];
  float4 A1 = wp[1];
  float4 B0 = wp[2];
  float4 B1 = wp[3];
  float wvA[BLOCK] = {A0.x, A0.y, A0.z, A0.w, A1.x, A1.y, A1.z, A1.w};
  float wvB[BLOCK] = {B0.x, B0.y, B0.z, B0.w, B1.x, B1.y, B1.z, B1.w};

  float aA[BLOCK], aB[BLOCK];
  unsigned sbA = 0u, sbB = 0u;
#pragma unroll
  for (int i = 0; i < BLOCK; ++i) {
    unsigned ua = __float_as_uint(wvA[i]);
    unsigned ub = __float_as_uint(wvB[i]);
    sbA |= (ua >> 31) << i;
    sbB |= (ub >> 31) << i;
    aA[i] = __uint_as_float(ua & 0x7fffffffu);  // == fabsf
    aB[i] = __uint_as_float(ub & 0x7fffffffu);
  }

  float gbA = -1.0f, gbB = -1.0f;
  int gkA = 0, gkB = 0;

#pragma unroll 1
  for (int c = 0; c < 32; ++c) {
    // 12 x ds_read_b128, wave-uniform address (broadcast, conflict-free);
    // issued together so the compiler batches them under one lgkm window.
    const float4* lt = reinterpret_cast<const float4*>(lds_f + c * 48);
    float4 t4[12];
#pragma unroll
    for (int q = 0; q < 12; ++q) t4[q] = lt[q];

    // static scatter to a named float[48] (all indices compile-time ->
    // stays in registers; pure copies, mostly folded by regalloc)
    float tb[48];
#pragma unroll
    for (int q = 0; q < 12; ++q) {
      tb[4 * q + 0] = t4[q].x;
      tb[4 * q + 1] = t4[q].y;
      tb[4 * q + 2] = t4[q].z;
      tb[4 * q + 3] = t4[q].w;
    }

    chunk_step(tb, aA, gbA, gkA);
    chunk_step(tb, aB, gbB, gkB);
  }

  float4 oA0, oA1, oB0, oB1;
  epilogue(aA, sbA, gkA, oA0, oA1);
  epilogue(aB, sbB, gkB, oB0, oB1);

  float4* op = reinterpret_cast<float4*>(out) + (size_t)4 * t;
  op[0] = oA0;
  op[1] = oA1;
  op[2] = oB0;
  op[3] = oB1;
}

extern "C" void kernel_launch(void* const* d_in, const int* in_sizes, int n_in,
                              void* d_out, int out_size, void* d_ws, size_t ws_size,
                              hipStream_t stream) {
  (void)n_in; (void)d_ws; (void)ws_size; (void)out_size;
  const float* w = (const float*)d_in[0];
  float* out = (float*)d_out;
  int n = in_sizes[0];
  int nb = n / BLOCK;      // 8-elem quant blocks (524288: even)
  int nt = nb / 2;         // 2 blocks per thread
  int threads = 256;
  int blocks = (nt + threads - 1) / threads;
  _IQ2XSQuantWeight_12945031430379_kernel<<<blocks, threads, 0, stream>>>(w, out, nt);
}